// Round 1
// baseline (61.839 us; speedup 1.0000x reference)
//
#include <hip/hip_runtime.h>

// RoPE: out[b,s,2k]   = cos(a)*x[b,s,2k] - sin(a)*x[b,s,2k+1]
//       out[b,s,2k+1] = sin(a)*x[b,s,2k] + cos(a)*x[b,s,2k+1]
// with a = pos[s] * theta^(-2k/d_k), d_k = 128, theta = 10000.
//
// One thread per float4 (= 2 rotation pairs). Fully coalesced 16B/lane.
// inv_freq computed inline: theta^(-2k/128) = exp2(-k * log2(theta)/64).

#define D_K 128

__global__ __launch_bounds__(256) void rope_kernel(
    const float4* __restrict__ x4,
    const int*    __restrict__ pos,
    float4*       __restrict__ out4,
    int n4, int seq)
{
    int i = blockIdx.x * blockDim.x + threadIdx.x;
    if (i >= n4) return;

    int flat = i * 4;                    // flat element index of x
    int d    = flat & (D_K - 1);         // lane within head dim (multiple of 4)
    int s    = (flat / D_K) % seq;       // token index
    float p  = (float)pos[s];

    // log2(10000)/64 = 13.287712379549449 / 64
    const float L = 0.20762050593046014f;
    int   k0 = d >> 1;                   // first pair index in this float4
    float a0 = p * exp2f(-L * (float)k0);
    float a1 = p * exp2f(-L * (float)(k0 + 1));

    float s0, c0, s1, c1;
    sincosf(a0, &s0, &c0);
    sincosf(a1, &s1, &c1);

    float4 v = x4[i];
    float4 o;
    o.x = c0 * v.x - s0 * v.y;
    o.y = s0 * v.x + c0 * v.y;
    o.z = c1 * v.z - s1 * v.w;
    o.w = s1 * v.z + c1 * v.w;
    out4[i] = o;
}

extern "C" void kernel_launch(void* const* d_in, const int* in_sizes, int n_in,
                              void* d_out, int out_size, void* d_ws, size_t ws_size,
                              hipStream_t stream) {
    const float4* x4  = (const float4*)d_in[0];
    const int*    pos = (const int*)d_in[1];
    float4*       o4  = (float4*)d_out;

    int n   = in_sizes[0];       // total fp32 elements of x
    int seq = in_sizes[1];       // 4096
    int n4  = n / 4;

    int block = 256;
    int grid  = (n4 + block - 1) / block;
    rope_kernel<<<grid, block, 0, stream>>>(x4, pos, o4, n4, seq);
}

// Round 2
// 61.048 us; speedup vs baseline: 1.0130x; 1.0130x over previous
//
#include <hip/hip_runtime.h>

// RoPE, fp32, d_k=128, theta=10000.
// out[..,2k]   = cos(a)*x[..,2k] - sin(a)*x[..,2k+1]
// out[..,2k+1] = sin(a)*x[..,2k] + cos(a)*x[..,2k+1],  a = pos[s]*theta^(-k/64)
//
// One thread per float4 (2 rotation pairs), fully coalesced 16B/lane.
// Trig via hardware v_sin_f32/v_cos_f32 in the REVOLUTIONS domain:
//   rev = (pos/2pi) * theta^(-k/64);  r = fract(rev);  sin(2*pi*r), cos(2*pi*r)
// Explicit fract is required: |rev| can reach ~651, outside the HW valid range.
// Precision: ~1e-3 rad angle error -> ~5e-3 output error vs 0.114 threshold.

#define D_K 128

__global__ __launch_bounds__(256) void rope_kernel(
    const float4* __restrict__ x4,
    const int*    __restrict__ pos,
    float4*       __restrict__ out4,
    int n4, int seq)
{
    int i = blockIdx.x * blockDim.x + threadIdx.x;
    if (i >= n4) return;

    int flat = i * 4;                    // flat element index of x
    int d    = flat & (D_K - 1);         // lane within head dim (multiple of 4)
    int s    = (flat / D_K) % seq;       // token index

    // p_rev = pos / (2*pi)
    float p_rev = (float)pos[s] * 0.15915494309189535f;

    // inv_freq(k) = theta^(-k/64) = exp2(-k * log2(theta)/64)
    const float L    = 0.20762050593046014f;   // log2(10000)/64
    const float STEP = 0.86596432336006535f;   // theta^(-1/64) = exp2(-L)
    int   k0 = d >> 1;
    float f0 = __builtin_amdgcn_exp2f(-L * (float)k0);
    float f1 = f0 * STEP;

    float r0 = __builtin_amdgcn_fractf(p_rev * f0);
    float r1 = __builtin_amdgcn_fractf(p_rev * f1);

    float s0 = __builtin_amdgcn_sinf(r0);   // sin(2*pi*r0)
    float c0 = __builtin_amdgcn_cosf(r0);
    float s1 = __builtin_amdgcn_sinf(r1);
    float c1 = __builtin_amdgcn_cosf(r1);

    float4 v = x4[i];
    float4 o;
    o.x = c0 * v.x - s0 * v.y;
    o.y = s0 * v.x + c0 * v.y;
    o.z = c1 * v.z - s1 * v.w;
    o.w = s1 * v.z + c1 * v.w;
    out4[i] = o;
}

extern "C" void kernel_launch(void* const* d_in, const int* in_sizes, int n_in,
                              void* d_out, int out_size, void* d_ws, size_t ws_size,
                              hipStream_t stream) {
    const float4* x4  = (const float4*)d_in[0];
    const int*    pos = (const int*)d_in[1];
    float4*       o4  = (float4*)d_out;

    int n   = in_sizes[0];       // total fp32 elements of x (4*4096*128)
    int seq = in_sizes[1];       // 4096
    int n4  = n / 4;

    int block = 256;
    int grid  = (n4 + block - 1) / block;
    rope_kernel<<<grid, block, 0, stream>>>(x4, pos, o4, n4, seq);
}